// Round 7
// baseline (747.248 us; speedup 1.0000x reference)
//
#include <hip/hip_runtime.h>

#define N_NODES 50000
#define N_EDGES 100000
#define DD 32
#define STEPS 5

#define NPT 4            // nodes per thread (gru)
#define NPB 128          // nodes per block (gru)
#define CAT_STRIDE 100   // floats per cat row (96 + 4 pad)
#define CHUNK 196        // scan: 256*196 = 50176 >= N_NODES

// prop[n,j] = emb[token[n],j]; also zero deg / cnt2 for the CSR build.
__global__ void init_prop(const int* __restrict__ token,
                          const float* __restrict__ emb,
                          float* __restrict__ prop,
                          unsigned* __restrict__ deg,
                          unsigned* __restrict__ cnt2) {
    int idx = blockIdx.x * 256 + threadIdx.x;   // over N*D = 1.6M, exact grid
    int n = idx >> 5, j = idx & 31;
    prop[idx] = emb[token[n] * DD + j];
    if (idx < N_NODES) deg[idx] = 0u;
    else if (idx < N_NODES + 2 * N_NODES) cnt2[idx - N_NODES] = 0u;
}

// Histogram: in-degree per dst node; packed-byte out-edge-type counts per src.
__global__ void build_hist(const int* __restrict__ etype,
                           const int* __restrict__ src,
                           const int* __restrict__ dst,
                           unsigned* __restrict__ deg,
                           unsigned* __restrict__ cnt2) {
    int e = blockIdx.x * 256 + threadIdx.x;
    if (e >= N_EDGES) return;
    atomicAdd(&deg[dst[e]], 1u);
    int t = etype[e], s = src[e];
    atomicAdd(&cnt2[s * 2 + (t >> 2)], 1u << (8 * (t & 3)));  // max count << 255
}

// Transpose W_edge[t,i,j,k] into Wf[t,i,j] (k=0) and Wrv[t,i,j] (k=1).
// 8192 pairs total -> EXACTLY 32 blocks x 256 (R6 bug: 64 blocks overflowed
// Wf into Wrv's storage with OOB garbage).
__global__ void prep_W(const float* __restrict__ W_edge,
                       float* __restrict__ Wf, float* __restrict__ Wrv) {
    int idx = blockIdx.x * 256 + threadIdx.x;   // 32 * 256 = 8192 exact
    Wf[idx]  = W_edge[idx * 2];
    Wrv[idx] = W_edge[idx * 2 + 1];
}

// Single-block exclusive scan of deg -> off (and cursor copy). off[N]=E.
__global__ __launch_bounds__(256) void
scan_kernel(const unsigned* __restrict__ deg,
            unsigned* __restrict__ off, unsigned* __restrict__ cursor) {
    __shared__ unsigned part[256];
    int t = threadIdx.x;
    int lo = t * CHUNK, hi = min(lo + CHUNK, N_NODES);
    unsigned s = 0;
    for (int n = lo; n < hi; ++n) s += deg[n];
    part[t] = s;
    __syncthreads();
    for (int d = 1; d < 256; d <<= 1) {       // Hillis-Steele inclusive scan
        unsigned v = (t >= d) ? part[t - d] : 0u;
        __syncthreads();
        part[t] += v;
        __syncthreads();
    }
    unsigned run = part[t] - s;               // exclusive base for this chunk
    for (int n = lo; n < hi; ++n) {
        off[n] = run; cursor[n] = run;
        run += deg[n];
    }
    if (hi == N_NODES && lo < N_NODES) off[N_NODES] = run;   // = N_EDGES
}

// Scatter edges into CSR-by-dst, packing (src<<3 | etype).
__global__ void scatter_edges(const int* __restrict__ etype,
                              const int* __restrict__ src,
                              const int* __restrict__ dst,
                              unsigned* __restrict__ cursor,
                              unsigned* __restrict__ eid) {
    int e = blockIdx.x * 256 + threadIdx.x;
    if (e >= N_EDGES) return;
    unsigned p = atomicAdd(&cursor[dst[e]], 1u);
    eid[p] = ((unsigned)src[e] << 3) | (unsigned)etype[e];
}

// Half-wave (32 lanes) per node, lane j = output column. No atomics:
//   in_fea[n]  = sum over CSR in-edges of prop[src] @ Wf[etype]
//   out_fea[n] = sum_t cnt_out[n,t] * (prop[n] @ Wrv[t])   (type-count trick)
__global__ void message_kernel(const unsigned* __restrict__ off,
                               const unsigned* __restrict__ eid,
                               const unsigned* __restrict__ cnt2,
                               const float* __restrict__ Wf,
                               const float* __restrict__ Wrv,
                               const float* __restrict__ prop,
                               float* __restrict__ in_fea,
                               float* __restrict__ out_fea) {
    int n = blockIdx.x * 8 + (threadIdx.x >> 5);   // 6250 * 8 = 50000 exact
    int lane = threadIdx.x & 63;
    int j = threadIdx.x & 31;
    int base = lane & 32;
    float p = prop[n * DD + j];
    unsigned o0 = off[n], o1 = off[n + 1];
    float accI = 0.f;
    for (unsigned q = o0; q < o1; ++q) {
        unsigned v = eid[q];                        // broadcast load
        int s = v >> 3, t = v & 7;
        float h = prop[s * DD + j];                 // coalesced 128B gather
        const float* W = Wf + t * (DD * DD);
        float a = 0.f;
#pragma unroll
        for (int i = 0; i < DD; ++i)
            a = fmaf(__shfl(h, base + i), W[i * DD + j], a);
        accI += a;
    }
    in_fea[n * DD + j] = accI;

    unsigned c0 = cnt2[n * 2], c1 = cnt2[n * 2 + 1];
    float accO = 0.f;
#pragma unroll
    for (int t = 0; t < 8; ++t) {
        unsigned cnt = ((t < 4 ? c0 : c1) >> (8 * (t & 3))) & 0xFFu;
        if (cnt) {
            const float* W = Wrv + t * (DD * DD);
            float a = 0.f;
#pragma unroll
            for (int i = 0; i < DD; ++i)
                a = fmaf(__shfl(p, base + i), W[i * DD + j], a);
            accO = fmaf((float)cnt, a, accO);
        }
    }
    out_fea[n * DD + j] = accO;
}

__device__ __forceinline__ void fma4(float (&acc)[4], float c, const float4& w) {
    acc[0] = fmaf(c, w.x, acc[0]);
    acc[1] = fmaf(c, w.y, acc[1]);
    acc[2] = fmaf(c, w.z, acc[2]);
    acc[3] = fmaf(c, w.w, acc[3]);
}
__device__ __forceinline__ float sigm(float x) {
    return 1.f / (1.f + __expf(-x));
}
__device__ __forceinline__ float fast_tanh(float x) {
    x = fminf(fmaxf(x, -15.f), 15.f);
    float e = __expf(2.f * x);
    return (e - 1.f) / (e + 1.f);
}

// Block = 256 threads = 128 nodes; cat=[in|out|prop] staged to LDS.
__global__ __launch_bounds__(256) void
gru_kernel(const float* __restrict__ W_r, const float* __restrict__ b_r,
           const float* __restrict__ W_z, const float* __restrict__ b_z,
           const float* __restrict__ W_t, const float* __restrict__ b_t,
           const float* __restrict__ in_fea,
           const float* __restrict__ out_fea,
           float* __restrict__ prop,
           float* __restrict__ out2) {
    __shared__ float cat[NPB * CAT_STRIDE];           // 51.2 KB
    float4* cat4 = (float4*)cat;                      // row stride 25 float4
    const int tid = threadIdx.x;
    const int n0 = blockIdx.x * NPB;
    const int jq = tid & 7;
    const int ng = tid >> 3;

    {
        const float4* a4 = (const float4*)(in_fea  + (size_t)n0 * DD);
        const float4* b4 = (const float4*)(out_fea + (size_t)n0 * DD);
        const float4* p4 = (const float4*)(prop    + (size_t)n0 * DD);
        const float4 zz = {0.f, 0.f, 0.f, 0.f};
#pragma unroll
        for (int q = 0; q < 4; ++q) {
            int f = q * 256 + tid;
            int node = f >> 3;
            int c4 = f & 7;
            bool ok = (n0 + node) < N_NODES;
            cat4[node * 25 + c4]      = ok ? a4[f] : zz;
            cat4[node * 25 + 8 + c4]  = ok ? b4[f] : zz;
            cat4[node * 25 + 16 + c4] = ok ? p4[f] : zz;
        }
    }
    __syncthreads();

    // ---- phase A: r,z ----
    float r_[NPT][4], z_[NPT][4];
    {
        float4 br = ((const float4*)b_r)[jq];
        float4 bz = ((const float4*)b_z)[jq];
#pragma unroll
        for (int k = 0; k < NPT; ++k) {
            r_[k][0] = br.x; r_[k][1] = br.y; r_[k][2] = br.z; r_[k][3] = br.w;
            z_[k][0] = bz.x; z_[k][1] = bz.y; z_[k][2] = bz.z; z_[k][3] = bz.w;
        }
    }
#pragma unroll 1
    for (int g = 0; g < 24; ++g) {
        int m0 = g * 4;
        float4 wr[4], wz[4];
#pragma unroll
        for (int i = 0; i < 4; ++i) {
            wr[i] = ((const float4*)(W_r + (m0 + i) * DD))[jq];
            wz[i] = ((const float4*)(W_z + (m0 + i) * DD))[jq];
        }
#pragma unroll
        for (int k = 0; k < NPT; ++k) {
            float4 c = cat4[(ng + 32 * k) * 25 + g];
            fma4(r_[k], c.x, wr[0]); fma4(r_[k], c.y, wr[1]);
            fma4(r_[k], c.z, wr[2]); fma4(r_[k], c.w, wr[3]);
            fma4(z_[k], c.x, wz[0]); fma4(z_[k], c.y, wz[1]);
            fma4(z_[k], c.z, wz[2]); fma4(z_[k], c.w, wz[3]);
        }
    }

    float p_[NPT][4];
#pragma unroll
    for (int k = 0; k < NPT; ++k) {
        float4 p = cat4[(ng + 32 * k) * 25 + 16 + jq];
        p_[k][0] = p.x; p_[k][1] = p.y; p_[k][2] = p.z; p_[k][3] = p.w;
#pragma unroll
        for (int j = 0; j < 4; ++j) {
            r_[k][j] = sigm(r_[k][j]) * p_[k][j];     // r := r*p
            z_[k][j] = sigm(z_[k][j]);
        }
    }
    __syncthreads();
#pragma unroll
    for (int k = 0; k < NPT; ++k) {
        float4 rp = {r_[k][0], r_[k][1], r_[k][2], r_[k][3]};
        cat4[(ng + 32 * k) * 25 + 16 + jq] = rp;
    }
    __syncthreads();

    // ---- phase B: t ----
    float t_[NPT][4];
    {
        float4 bt = ((const float4*)b_t)[jq];
#pragma unroll
        for (int k = 0; k < NPT; ++k) {
            t_[k][0] = bt.x; t_[k][1] = bt.y; t_[k][2] = bt.z; t_[k][3] = bt.w;
        }
    }
#pragma unroll 1
    for (int g = 0; g < 24; ++g) {
        int m0 = g * 4;
        float4 wt[4];
#pragma unroll
        for (int i = 0; i < 4; ++i)
            wt[i] = ((const float4*)(W_t + (m0 + i) * DD))[jq];
#pragma unroll
        for (int k = 0; k < NPT; ++k) {
            float4 c = cat4[(ng + 32 * k) * 25 + g];
            fma4(t_[k], c.x, wt[0]); fma4(t_[k], c.y, wt[1]);
            fma4(t_[k], c.z, wt[2]); fma4(t_[k], c.w, wt[3]);
        }
    }

    // ---- update: prop = p + z*(tanh(t) - p); final step also writes out2 ----
#pragma unroll
    for (int k = 0; k < NPT; ++k) {
        int node = n0 + ng + 32 * k;
        if (node < N_NODES) {
            float4 o;
            o.x = fmaf(z_[k][0], fast_tanh(t_[k][0]) - p_[k][0], p_[k][0]);
            o.y = fmaf(z_[k][1], fast_tanh(t_[k][1]) - p_[k][1], p_[k][1]);
            o.z = fmaf(z_[k][2], fast_tanh(t_[k][2]) - p_[k][2], p_[k][2]);
            o.w = fmaf(z_[k][3], fast_tanh(t_[k][3]) - p_[k][3], p_[k][3]);
            ((float4*)(prop + (size_t)node * DD))[jq] = o;
            if (out2) ((float4*)(out2 + (size_t)node * DD))[jq] = o;
        }
    }
}

extern "C" void kernel_launch(void* const* d_in, const int* in_sizes, int n_in,
                              void* d_out, int out_size, void* d_ws, size_t ws_size,
                              hipStream_t stream) {
    const int*   token  = (const int*)d_in[0];
    const int*   etype  = (const int*)d_in[1];
    const int*   src    = (const int*)d_in[2];
    const int*   dst    = (const int*)d_in[3];
    const float* emb    = (const float*)d_in[4];
    const float* W_edge = (const float*)d_in[5];
    const float* W_r    = (const float*)d_in[6];
    const float* b_r    = (const float*)d_in[7];
    const float* W_z    = (const float*)d_in[8];
    const float* b_z    = (const float*)d_in[9];
    const float* W_t    = (const float*)d_in[10];
    const float* b_t    = (const float*)d_in[11];
    float* out = (float*)d_out;

    // workspace layout (4-byte units), ~20.7 MB total
    float*    prop    = (float*)d_ws;                    // 1,600,000 f
    float*    in_fea  = prop + 1600000;                  // 1,600,000 f
    float*    out_fea = in_fea + 1600000;                // 1,600,000 f
    float*    Wf      = out_fea + 1600000;               // 8192 f
    float*    Wrv     = Wf + 8192;                       // 8192 f
    unsigned* off     = (unsigned*)(Wrv + 8192);         // 50,016 u32
    unsigned* cursor  = off + 50016;                     // 50,016 u32
    unsigned* deg     = cursor + 50016;                  // 50,016 u32
    unsigned* cnt2    = deg + 50016;                     // 100,000 u32
    unsigned* eid     = cnt2 + 100000;                   // 100,000 u32

    // ---- one-time build phase (amortized over 5 steps) ----
    init_prop<<<(N_NODES * DD) / 256, 256, 0, stream>>>(token, emb, prop, deg, cnt2);
    build_hist<<<(N_EDGES + 255) / 256, 256, 0, stream>>>(etype, src, dst, deg, cnt2);
    prep_W<<<32, 256, 0, stream>>>(W_edge, Wf, Wrv);     // 8192 pairs EXACT
    scan_kernel<<<1, 256, 0, stream>>>(deg, off, cursor);
    scatter_edges<<<(N_EDGES + 255) / 256, 256, 0, stream>>>(etype, src, dst,
                                                             cursor, eid);
    // ---- propagation ----
    for (int step = 0; step < STEPS; ++step) {
        message_kernel<<<N_NODES / 8, 256, 0, stream>>>(off, eid, cnt2, Wf, Wrv,
                                                        prop, in_fea, out_fea);
        gru_kernel<<<(N_NODES + NPB - 1) / NPB, 256, 0, stream>>>(
            W_r, b_r, W_z, b_z, W_t, b_t, in_fea, out_fea, prop,
            (step == STEPS - 1) ? out : nullptr);
    }
}